// Round 12
// baseline (1077.809 us; speedup 1.0000x reference)
//
#include <hip/hip_runtime.h>
#include <hip/hip_bf16.h>

// Problem constants (Llama-ish decoder, 2 layers, prefill)
constexpr int kL = 2;
constexpr int kS = 2048;   // seq
constexpr int kH = 2048;   // hidden
constexpr int kNH = 16;    // heads
constexpr int kD = 128;    // head dim
constexpr int kI = 5632;   // intermediate

using s16x8 = __attribute__((ext_vector_type(8))) short;
using s16x4 = __attribute__((ext_vector_type(4))) short;
using f32x4 = __attribute__((ext_vector_type(4))) float;

// bf16 helpers (bf16 stored as short)
__device__ __forceinline__ float b2f(short s) {
  union { unsigned u; float f; } v;
  v.u = ((unsigned)(unsigned short)s) << 16;
  return v.f;
}
__device__ __forceinline__ short f2bs(float f) {
  __hip_bfloat16 h = __float2bfloat16(f);   // RNE
  union { __hip_bfloat16 h; short s; } u;
  u.h = h;
  return u.s;
}

// async global->LDS, 16B per lane; LDS dest is wave-uniform base + lane*16
__device__ __forceinline__ void lds16(const void* g, void* l) {
  __builtin_amdgcn_global_load_lds(
      (const __attribute__((address_space(1))) void*)g,
      (__attribute__((address_space(3))) void*)l, 16, 0, 0);
}

// raw barrier: no compiler-inserted vmcnt(0) drain; "memory" clobber keeps
// LDS/global ops from crossing (rule #18: pin with sched_barrier at call site)
__device__ __forceinline__ void raw_barrier() {
  asm volatile("s_barrier" ::: "memory");
}

// 2D XCD chunking, rows-fastest within each XCD rect (r9-verified: FETCH 233->96MB)
__device__ __forceinline__ void swz_block(int gx, int& bx, int& by) {
  const int gy = gridDim.y;
  const int lin = by * gx + bx;
  if ((gx & 3) == 0 && (gy & 1) == 0) {
    const int cx = gx >> 2, cy = gy >> 1;
    const int xcd = lin & 7;
    const int s = lin >> 3;
    bx = (xcd & 3) * cx + s / cy;        // column advances slowest
    by = (xcd >> 2) * cy + s % cy;       // row advances fastest
  } else if (((gx * gy) & 7) == 0) {
    const int cpx = (gx * gy) >> 3;
    const int l2 = (lin & 7) * cpx + (lin >> 3);
    bx = l2 % gx;
    by = l2 / gx;
  }
}

// ---------------------------------------------------------------------------
// fused fp32 -> bf16 conversion of all 7 weight matrices of one layer.
// ---------------------------------------------------------------------------
__global__ __launch_bounds__(256) void cvt_all(const float* __restrict__ q,
                                               const float* __restrict__ k,
                                               const float* __restrict__ v,
                                               const float* __restrict__ o,
                                               const float* __restrict__ g,
                                               const float* __restrict__ u,
                                               const float* __restrict__ d,
                                               short* __restrict__ dst) {
  constexpr int HH8 = (kH * kH) / 8;       // 524288 (pow2)
  constexpr int IH8 = (kI * kH) / 8;       // 1441792
  constexpr int tot = 4 * HH8 + 3 * IH8;
  for (int i = blockIdx.x * blockDim.x + threadIdx.x; i < tot; i += gridDim.x * blockDim.x) {
    const float* src;
    int off;
    if (i < 4 * HH8) {
      const int s = i >> 19;               // / HH8
      off = i & (HH8 - 1);
      src = s == 0 ? q : s == 1 ? k : s == 2 ? v : o;
    } else {
      const int j = i - 4 * HH8;
      const int s = j / IH8;
      off = j - s * IH8;
      src = s == 0 ? g : s == 1 ? u : d;
    }
    const float4 a = ((const float4*)src)[2 * off];
    const float4 b = ((const float4*)src)[2 * off + 1];
    s16x8 ov;
    ov[0] = f2bs(a.x); ov[1] = f2bs(a.y); ov[2] = f2bs(a.z); ov[3] = f2bs(a.w);
    ov[4] = f2bs(b.x); ov[5] = f2bs(b.y); ov[6] = f2bs(b.z); ov[7] = f2bs(b.w);
    ((s16x8*)dst)[i] = ov;
  }
}

// ---------------------------------------------------------------------------
// 128x128 GEMM (bf16 x bf16): C[M,N] = A[M,K] * B[N,K]^T. BK=64, 4 waves,
// double-buffered LDS (64KB, 2 blocks/CU), XOR swizzle.
// NEW (r12): counted-vmcnt ring schedule — no vmcnt(0) drain in the loop.
//   prologue: stage tile0, tile1  (8 loads each, in-order vmem retirement)
//   per tile T: vmcnt(8 if T+1 exists else 0)  // T's loads issued 2 iters ago
//               raw_barrier; compute(T); raw_barrier; stage(T+2)
// EPI: 1 = fp32 residual add; 3 = fused QKV; 4 = fused gate+up
// ---------------------------------------------------------------------------
template <int EPI>
__global__ __launch_bounds__(256) void gemm_db(const short* __restrict__ A,
                                               const short* __restrict__ B,
                                               short* __restrict__ C0,
                                               short* __restrict__ C1,
                                               short* __restrict__ C2,
                                               float* __restrict__ Cf,
                                               int M, int N, int K) {
  __shared__ short As0[128 * 64], Bs0[128 * 64];
  __shared__ short As1[128 * 64], Bs1[128 * 64];
  const int t = threadIdx.x;
  const int lane = t & 63, wid = t >> 6;
  int bx = blockIdx.x, by = blockIdx.y;
  swz_block(gridDim.x, bx, by);
  const int m0 = by * 128, n0 = bx * 128;
  const int wr = (wid >> 1) * 64, wc = (wid & 1) * 64;
  const int fr = lane & 15, g4 = lane >> 4;

  const int srow = (lane >> 3);
  const int scol = (((lane & 7) << 4) ^ (srow << 4)) >> 1;  // pre-swizzled col

  f32x4 acc[4][4] = {};

  auto stage = [&](short* Ad, short* Bd, int k0) {   // 8 vmem issues per thread
    #pragma unroll
    for (int c = 0; c < 4; ++c) {
      const int chunk = wid * 4 + c;
      const int e0 = chunk * 512;
      const int row = chunk * 8 + srow;
      lds16(A + (size_t)(m0 + row) * K + k0 + scol, Ad + e0);
      lds16(B + (size_t)(n0 + row) * K + k0 + scol, Bd + e0);
    }
  };

  auto compute = [&](const short* Xs, const short* Ys) {
    #pragma unroll
    for (int ks = 0; ks < 2; ++ks) {
      s16x8 a[4], b[4];
      #pragma unroll
      for (int m = 0; m < 4; ++m) {
        const int r = wr + m * 16 + fr;
        a[m] = *(const s16x8*)&Xs[r * 64 + (((ks * 4 + g4) ^ (r & 7)) << 3)];
      }
      #pragma unroll
      for (int n = 0; n < 4; ++n) {
        const int r = wc + n * 16 + fr;
        b[n] = *(const s16x8*)&Ys[r * 64 + (((ks * 4 + g4) ^ (r & 7)) << 3)];
      }
      __builtin_amdgcn_s_setprio(1);
      #pragma unroll
      for (int m = 0; m < 4; ++m)
        #pragma unroll
        for (int n = 0; n < 4; ++n)
          acc[m][n] = __builtin_amdgcn_mfma_f32_16x16x32_bf16(a[m], b[n], acc[m][n], 0, 0, 0);
      __builtin_amdgcn_s_setprio(0);
    }
  };

  const int nt = K >> 6;                 // >= 32 for all our shapes
  stage(As0, Bs0, 0);
  stage(As1, Bs1, 64);
  for (int T = 0; T < nt; ++T) {
    // wait for tile T's 8 loads: allowed in-flight = tile T+1's 8 (newest).
    if (T + 1 < nt) asm volatile("s_waitcnt vmcnt(8)" ::: "memory");
    else            asm volatile("s_waitcnt vmcnt(0)" ::: "memory");
    __builtin_amdgcn_sched_barrier(0);
    raw_barrier();                       // all waves verified their own loads
    if (T & 1) compute(As1, Bs1);
    else       compute(As0, Bs0);
    raw_barrier();                       // all waves done reading this buffer
    __builtin_amdgcn_sched_barrier(0);
    if (T + 2 < nt) {
      if (T & 1) stage(As1, Bs1, (T + 2) << 6);
      else       stage(As0, Bs0, (T + 2) << 6);
    }
  }

  #pragma unroll
  for (int m = 0; m < 4; ++m) {
    #pragma unroll
    for (int n = 0; n < 4; ++n) {
      const int rb = m0 + wr + m * 16 + g4 * 4;
      const int col = n0 + wc + n * 16 + fr;
      if (EPI == 1) {
        #pragma unroll
        for (int j = 0; j < 4; ++j)
          Cf[(size_t)(rb + j) * N + col] += acc[m][n][j];
      } else if (EPI == 3) {
        const int seg = n0 >> 11;        // block-uniform
        const int cl = col - (seg << 11);
        if (seg == 0) {
          #pragma unroll
          for (int j = 0; j < 4; ++j) C0[(size_t)(rb + j) * 2048 + cl] = f2bs(acc[m][n][j]);
        } else if (seg == 1) {
          #pragma unroll
          for (int j = 0; j < 4; ++j) C1[(size_t)(rb + j) * 2048 + cl] = f2bs(acc[m][n][j]);
        } else {
          s16x4 pk;
          #pragma unroll
          for (int j = 0; j < 4; ++j) pk[j] = f2bs(acc[m][n][j]);
          *(s16x4*)&C2[(size_t)cl * M + rb] = pk;   // V^T
        }
      } else {  // EPI == 4
        const bool useg = (n0 >= 5632);
        const int cl = col - (useg ? 5632 : 0);
        short* dst = useg ? C1 : C0;
        #pragma unroll
        for (int j = 0; j < 4; ++j) dst[(size_t)(rb + j) * 5632 + cl] = f2bs(acc[m][n][j]);
      }
    }
  }
}

// ---------------------------------------------------------------------------
// Fallback GEMM (bf16 A x fp32 B) — used only if workspace too small.
// ---------------------------------------------------------------------------
template <int EPI>
__global__ __launch_bounds__(256) void gemm_btf(const short* __restrict__ A,
                                                const float* __restrict__ B,
                                                short* __restrict__ Cb,
                                                float* __restrict__ Cf,
                                                int M, int N, int K) {
  __shared__ short As[128 * 32];
  __shared__ short Bs[128 * 32];
  const int t = threadIdx.x;
  const int lane = t & 63, wid = t >> 6;
  int bx = blockIdx.x, by = blockIdx.y;
  swz_block(gridDim.x, bx, by);
  const int m0 = by * 128, n0 = bx * 128;
  const int wr = (wid >> 1) * 64, wc = (wid & 1) * 64;
  const int fr = lane & 15, h8 = (lane >> 4) * 8;
  const int brow = t >> 1, bcol = (t & 1) * 16;
  const float* bsrc = B + (size_t)(n0 + brow) * K + bcol;

  f32x4 acc[4][4] = {};

  for (int k0 = 0; k0 < K; k0 += 32) {
    const float4 bv0 = *(const float4*)(bsrc + k0);
    const float4 bv1 = *(const float4*)(bsrc + k0 + 4);
    const float4 bv2 = *(const float4*)(bsrc + k0 + 8);
    const float4 bv3 = *(const float4*)(bsrc + k0 + 12);
    __syncthreads();
    {
      const float bf[16] = {bv0.x, bv0.y, bv0.z, bv0.w, bv1.x, bv1.y, bv1.z, bv1.w,
                            bv2.x, bv2.y, bv2.z, bv2.w, bv3.x, bv3.y, bv3.z, bv3.w};
      s16x8 wlo, whi;
      #pragma unroll
      for (int j = 0; j < 8; ++j) { wlo[j] = f2bs(bf[j]); whi[j] = f2bs(bf[8 + j]); }
      *(s16x8*)&Bs[brow * 32 + bcol] = wlo;
      *(s16x8*)&Bs[brow * 32 + bcol + 8] = whi;
    }
    #pragma unroll
    for (int c = 0; c < 2; ++c) {
      const int e0 = c * 2048 + wid * 512;
      const int e = e0 + lane * 8;
      const int row = e >> 5, col = e & 31;
      lds16(A + (size_t)(m0 + row) * K + k0 + col, (void*)(As + e0));
    }
    __syncthreads();

    s16x8 a[4], b[4];
    #pragma unroll
    for (int m = 0; m < 4; ++m) a[m] = *(const s16x8*)&As[(wr + m * 16 + fr) * 32 + h8];
    #pragma unroll
    for (int n = 0; n < 4; ++n) b[n] = *(const s16x8*)&Bs[(wc + n * 16 + fr) * 32 + h8];
    #pragma unroll
    for (int m = 0; m < 4; ++m)
      #pragma unroll
      for (int n = 0; n < 4; ++n)
        acc[m][n] = __builtin_amdgcn_mfma_f32_16x16x32_bf16(a[m], b[n], acc[m][n], 0, 0, 0);
  }

  const int g4 = lane >> 4;
  #pragma unroll
  for (int m = 0; m < 4; ++m) {
    #pragma unroll
    for (int n = 0; n < 4; ++n) {
      const int rb = m0 + wr + m * 16 + g4 * 4;
      const int col = n0 + wc + n * 16 + fr;
      if (EPI == 0) {
        #pragma unroll
        for (int j = 0; j < 4; ++j)
          Cb[(size_t)(rb + j) * N + col] = f2bs(acc[m][n][j]);
      } else if (EPI == 1) {
        #pragma unroll
        for (int j = 0; j < 4; ++j)
          Cf[(size_t)(rb + j) * N + col] += acc[m][n][j];
      } else {
        s16x4 pk;
        #pragma unroll
        for (int j = 0; j < 4; ++j) pk[j] = f2bs(acc[m][n][j]);
        *(s16x4*)&Cb[(size_t)col * M + rb] = pk;
      }
    }
  }
}

// ---------------------------------------------------------------------------
// RMSNorm: h = x / sqrt(mean(x^2)+eps) * w   (x fp32, w fp32, h bf16)
// ---------------------------------------------------------------------------
__global__ __launch_bounds__(256) void rmsnorm_k(const float* __restrict__ x,
                                                 const float* __restrict__ w,
                                                 short* __restrict__ h) {
  const int row = blockIdx.x, t = threadIdx.x;
  const float4* xr = (const float4*)(x + (size_t)row * kH);
  const float4 v0 = xr[2 * t], v1 = xr[2 * t + 1];
  float ss = v0.x * v0.x + v0.y * v0.y + v0.z * v0.z + v0.w * v0.w +
             v1.x * v1.x + v1.y * v1.y + v1.z * v1.z + v1.w * v1.w;
  #pragma unroll
  for (int off = 1; off < 64; off <<= 1) ss += __shfl_xor(ss, off);
  __shared__ float red[4];
  if ((t & 63) == 0) red[t >> 6] = ss;
  __syncthreads();
  ss = red[0] + red[1] + red[2] + red[3];
  const float rs = rsqrtf(ss * (1.0f / kH) + 1e-6f);
  const float4 w0 = ((const float4*)w)[2 * t];
  const float4 w1 = ((const float4*)w)[2 * t + 1];
  const float xv[8] = {v0.x, v0.y, v0.z, v0.w, v1.x, v1.y, v1.z, v1.w};
  const float wv[8] = {w0.x, w0.y, w0.z, w0.w, w1.x, w1.y, w1.z, w1.w};
  s16x8 o;
  #pragma unroll
  for (int j = 0; j < 8; ++j) o[j] = f2bs(xv[j] * rs * wv[j]);
  *(s16x8*)&h[(size_t)row * kH + t * 8] = o;
}

// ---------------------------------------------------------------------------
// RoPE in-place on q and k (bf16). cos/sin fp32 tables repeat halves.
// ---------------------------------------------------------------------------
__global__ __launch_bounds__(256) void rope_k(short* __restrict__ q, short* __restrict__ k,
                                              const float* __restrict__ cosb,
                                              const float* __restrict__ sinb,
                                              const int* __restrict__ pos) {
  const int s = blockIdx.x;
  const int p = pos[s];
  const size_t rowb = (size_t)s * kH;
  for (int idx = threadIdx.x; idx < kNH * 64; idx += 256) {
    const int hh = idx >> 6, d = idx & 63;
    const float c = cosb[p * kD + d];
    const float sn = sinb[p * kD + d];
    const size_t i1 = rowb + hh * kD + d, i2 = i1 + 64;
    const float q1 = b2f(q[i1]), q2 = b2f(q[i2]);
    q[i1] = f2bs(q1 * c - q2 * sn);
    q[i2] = f2bs(q2 * c + q1 * sn);
    const float k1 = b2f(k[i1]), k2 = b2f(k[i2]);
    k[i1] = f2bs(k1 * c - k2 * sn);
    k[i2] = f2bs(k2 * c + k1 * sn);
  }
}

// ---------------------------------------------------------------------------
// Flash attention, causal. Block = (head, 64-row Q tile), 4 waves x 16 rows.
// K/V double-buffered in LDS; T14 async-STAGE; one barrier per KV-step.
// ---------------------------------------------------------------------------
__global__ __launch_bounds__(256) void attn_k(const short* __restrict__ q,
                                              const short* __restrict__ k,
                                              const short* __restrict__ vt,
                                              short* __restrict__ o) {
  __shared__ short Kl[2][64 * 128];
  __shared__ short Vl[2][128 * 64];
  __shared__ short Pl[4][16 * 72];
  const int h = blockIdx.x;
  const int y = blockIdx.y;
  const int qi = (y < 16) ? y : 47 - y;    // balanced pairing
  const int t = threadIdx.x;
  const int lane = t & 63, wid = t >> 6;
  const int fr = lane & 15, g4 = lane >> 4;
  const int q0 = qi * 64 + wid * 16;

  s16x8 aq[4];
  {
    const short* qp = q + (size_t)(q0 + fr) * kH + h * kD;
    #pragma unroll
    for (int ks = 0; ks < 4; ++ks) aq[ks] = *(const s16x8*)(qp + ks * 32 + g4 * 8);
  }
  f32x4 acco[8] = {};
  float mrun[4], lrun[4];
  #pragma unroll
  for (int j = 0; j < 4; ++j) { mrun[j] = -3.0e30f; lrun[j] = 0.f; }

  s16x8 kreg[4], vreg[4];
  auto loadt = [&](int tt) {
    const int kv0 = tt * 64;
    #pragma unroll
    for (int c = 0; c < 4; ++c) {
      const int b = c * 4096 + t * 16;
      kreg[c] = *(const s16x8*)(k + (size_t)(kv0 + (b >> 8)) * kH + h * kD + ((b & 255) >> 1));
      vreg[c] = *(const s16x8*)(vt + (size_t)(h * kD + (b >> 7)) * kS + kv0 + ((b & 127) >> 1));
    }
  };
  auto writet = [&](int buf) {
    #pragma unroll
    for (int c = 0; c < 4; ++c) {
      const int b = c * 4096 + t * 16;
      const int kr = b >> 8, kc = b & 255;
      *(s16x8*)((char*)Kl[buf] + kr * 256 + (kc ^ ((kr & 7) << 4))) = kreg[c];
      const int vr = b >> 7, vc = b & 127;
      *(s16x8*)((char*)Vl[buf] + vr * 128 + (vc ^ ((vr & 7) << 4))) = vreg[c];
    }
  };

  loadt(0);
  writet(0);
  __syncthreads();

  for (int tt = 0; tt <= qi; ++tt) {
    const int kv0 = tt * 64;
    const int cur = tt & 1;
    if (tt < qi) loadt(tt + 1);            // issue early; lands during compute

    // QK^T : 16 q-rows x 64 kv
    f32x4 sc[4] = {};
    __builtin_amdgcn_s_setprio(1);
    #pragma unroll
    for (int ks = 0; ks < 4; ++ks) {
      const int ch16 = ks * 4 + g4;
      #pragma unroll
      for (int nf = 0; nf < 4; ++nf) {
        const int row = nf * 16 + fr;
        const s16x8 bk =
            *(const s16x8*)((const char*)Kl[cur] + row * 256 + ((ch16 ^ (row & 7)) << 4));
        sc[nf] = __builtin_amdgcn_mfma_f32_16x16x32_bf16(aq[ks], bk, sc[nf], 0, 0, 0);
      }
    }
    __builtin_amdgcn_s_setprio(0);

    float val[4][4];
    #pragma unroll
    for (int nf = 0; nf < 4; ++nf) {
      #pragma unroll
      for (int j = 0; j < 4; ++j) {
        float v = sc[nf][j] * 0.08838834764831845f;
        if (tt == qi) {
          const int colg = kv0 + nf * 16 + fr;
          const int rowg = q0 + g4 * 4 + j;
          if (colg > rowg) v -= 1.0e9f;
        }
        val[nf][j] = v;
      }
    }

    #pragma unroll
    for (int j = 0; j < 4; ++j) {
      float rm = fmaxf(fmaxf(val[0][j], val[1][j]), fmaxf(val[2][j], val[3][j]));
      rm = fmaxf(rm, __shfl_xor(rm, 1));
      rm = fmaxf(rm, __shfl_xor(rm, 2));
      rm = fmaxf(rm, __shfl_xor(rm, 4));
      rm = fmaxf(rm, __shfl_xor(rm, 8));
      const float mnew = fmaxf(mrun[j], rm);
      const float corr = __expf(mrun[j] - mnew);
      mrun[j] = mnew;
      float ps = 0.f;
      #pragma unroll
      for (int nf = 0; nf < 4; ++nf) {
        const float p = __expf(val[nf][j] - mnew);
        ps += p;
        Pl[wid][(g4 * 4 + j) * 72 + nf * 16 + fr] = f2bs(p);
      }
      ps += __shfl_xor(ps, 1);
      ps += __shfl_xor(ps, 2);
      ps += __shfl_xor(ps, 4);
      ps += __shfl_xor(ps, 8);
      lrun[j] = lrun[j] * corr + ps;
      #pragma unroll
      for (int nf = 0; nf < 8; ++nf) acco[nf][j] *= corr;
    }

    // PV: P(16x64) @ V(64x128)
    __builtin_amdgcn_s_setprio(1);
    #pragma unroll
    for (int ks = 0; ks < 2; ++ks) {
      const s16x8 ap = *(const s16x8*)(&Pl[wid][fr * 72 + ks * 32 + g4 * 8]);
      const int ch16 = ks * 4 + g4;
      #pragma unroll
      for (int nf = 0; nf < 8; ++nf) {
        const int dd = nf * 16 + fr;
        const s16x8 bv =
            *(const s16x8*)((const char*)Vl[cur] + dd * 128 + ((ch16 ^ (dd & 7)) << 4));
        acco[nf] = __builtin_amdgcn_mfma_f32_16x16x32_bf16(ap, bv, acco[nf], 0, 0, 0);
      }
    }
    __builtin_amdgcn_s_setprio(0);

    if (tt < qi) writet(cur ^ 1);          // write-late into the other buffer
    __syncthreads();                       // single barrier per KV-step
  }

  #pragma unroll
  for (int nf = 0; nf < 8; ++nf) {
    #pragma unroll
    for (int j = 0; j < 4; ++j) {
      const int rowg = q0 + g4 * 4 + j;
      o[(size_t)rowg * kH + h * kD + nf * 16 + fr] = f2bs(acco[nf][j] / lrun[j]);
    }
  }
}

// ---------------------------------------------------------------------------
// silu(gate) * up, in place into g (bf16)
// ---------------------------------------------------------------------------
__global__ void silu_mul(short* __restrict__ g, const short* __restrict__ u, int n8) {
  for (int i = blockIdx.x * blockDim.x + threadIdx.x; i < n8; i += gridDim.x * blockDim.x) {
    const s16x8 gv = ((const s16x8*)g)[i];
    const s16x8 uv = ((const s16x8*)u)[i];
    s16x8 o;
    #pragma unroll
    for (int j = 0; j < 8; ++j) {
      const float gf = b2f(gv[j]);
      const float s = gf / (1.f + __expf(-gf));
      o[j] = f2bs(s * b2f(uv[j]));
    }
    ((s16x8*)g)[i] = o;
  }
}

// ---------------------------------------------------------------------------
extern "C" void kernel_launch(void* const* d_in, const int* in_sizes, int n_in,
                              void* d_out, int out_size, void* d_ws, size_t ws_size,
                              hipStream_t stream) {
  (void)in_sizes; (void)n_in; (void)out_size;
  const float* hidden = (const float*)d_in[0];
  const float* cosb = (const float*)d_in[2];
  const float* sinb = (const float*)d_in[3];
  const float* wq = (const float*)d_in[4];
  const float* wk = (const float*)d_in[5];
  const float* wv = (const float*)d_in[6];
  const float* wo = (const float*)d_in[7];
  const float* wg = (const float*)d_in[8];
  const float* wu = (const float*)d_in[9];
  const float* wd = (const float*)d_in[10];
  const float* ln1 = (const float*)d_in[11];
  const float* ln2 = (const float*)d_in[12];
  const int* pos = (const int*)d_in[13];
  float* out = (float*)d_out;

  // workspace layout
  char* p = (char*)d_ws;
  float* x  = (float*)p;  p += (size_t)kS * kH * 4;   // fp32 residual (16.8MB)
  short* hb = (short*)p;  p += (size_t)kS * kH * 2;   // normed acts (8.4MB)
  char* U = p;            p += (size_t)kS * kI * 4;   // union region (46.1MB)
  short* qb = (short*)(U);
  short* kb = (short*)(U + (size_t)kS * kH * 2);
  short* vtb = (short*)(U + (size_t)kS * kH * 4);     // V^T [H][S]
  short* ob = (short*)(U + (size_t)kS * kH * 6);      // attention out
  short* gb = (short*)(U);                            // gate (MLP phase)
  short* ub = (short*)(U + (size_t)kS * kI * 2);      // up   (MLP phase)
  short* wbuf = (short*)p;                            // bf16 weights, one layer
  const size_t nHH = (size_t)kH * kH, nIH = (size_t)kI * kH;
  const size_t need = (size_t)(p - (char*)d_ws) + (4 * nHH + 3 * nIH) * 2;
  const bool pre = ws_size >= need;

  short* wqb = wbuf;            // q,k,v contiguous -> fused N=6144 B matrix
  short* wob = wqb + 3 * nHH;
  short* wgb = wob + nHH;       // gate,up contiguous -> fused N=11264 B matrix
  short* wdb = wgb + 2 * nIH;

  hipMemcpyAsync(x, hidden, (size_t)kS * kH * 4, hipMemcpyDeviceToDevice, stream);
  for (int l = 0; l < kL; ++l) {
    rmsnorm_k<<<kS, 256, 0, stream>>>(x, ln1 + (size_t)l * kH, hb);
    if (pre) {
      cvt_all<<<2048, 256, 0, stream>>>(wq + l * nHH, wk + l * nHH, wv + l * nHH,
                                        wo + l * nHH, wg + l * nIH, wu + l * nIH,
                                        wd + l * nIH, wbuf);
      // fused QKV: N = 6144 (grid 48x16 -> XCD rects 12x8)
      gemm_db<3><<<dim3(6144 / 128, kS / 128), 256, 0, stream>>>(
          hb, wqb, qb, kb, vtb, nullptr, kS, 6144, kH);
      rope_k<<<kS, 256, 0, stream>>>(qb, kb, cosb, sinb, pos);
      attn_k<<<dim3(kNH, kS / 64), 256, 0, stream>>>(qb, kb, vtb, ob);
      gemm_db<1><<<dim3(kH / 128, kS / 128), 256, 0, stream>>>(
          ob, wob, nullptr, nullptr, nullptr, x, kS, kH, kH);
      rmsnorm_k<<<kS, 256, 0, stream>>>(x, ln2 + (size_t)l * kH, hb);
      // fused gate+up: N = 11264 (grid 88x16 -> XCD rects 22x8)
      gemm_db<4><<<dim3(11264 / 128, kS / 128), 256, 0, stream>>>(
          hb, wgb, gb, ub, nullptr, nullptr, kS, 11264, kH);
      silu_mul<<<1408, 256, 0, stream>>>(gb, ub, kS * kI / 8);
      gemm_db<1><<<dim3(kH / 128, kS / 128), 256, 0, stream>>>(
          gb, wdb, nullptr, nullptr, nullptr, x, kS, kH, kI);
    } else {
      gemm_btf<0><<<dim3(kH / 128, kS / 128), 256, 0, stream>>>(hb, wq + l * nHH, qb, nullptr, kS, kH, kH);
      gemm_btf<0><<<dim3(kH / 128, kS / 128), 256, 0, stream>>>(hb, wk + l * nHH, kb, nullptr, kS, kH, kH);
      gemm_btf<2><<<dim3(kH / 128, kS / 128), 256, 0, stream>>>(hb, wv + l * nHH, vtb, nullptr, kS, kH, kH);
      rope_k<<<kS, 256, 0, stream>>>(qb, kb, cosb, sinb, pos);
      attn_k<<<dim3(kNH, kS / 64), 256, 0, stream>>>(qb, kb, vtb, ob);
      gemm_btf<1><<<dim3(kH / 128, kS / 128), 256, 0, stream>>>(ob, wo + l * nHH, nullptr, x, kS, kH, kH);
      rmsnorm_k<<<kS, 256, 0, stream>>>(x, ln2 + (size_t)l * kH, hb);
      gemm_btf<0><<<dim3(kI / 128, kS / 128), 256, 0, stream>>>(hb, wg + l * nIH, gb, nullptr, kS, kI, kH);
      gemm_btf<0><<<dim3(kI / 128, kS / 128), 256, 0, stream>>>(hb, wu + l * nIH, ub, nullptr, kS, kI, kH);
      silu_mul<<<1408, 256, 0, stream>>>(gb, ub, kS * kI / 8);
      gemm_btf<1><<<dim3(kH / 128, kS / 128), 256, 0, stream>>>(gb, wd + l * nIH, nullptr, x, kS, kH, kI);
    }
  }
  hipMemcpyAsync(out, x, (size_t)kS * kH * 4, hipMemcpyDeviceToDevice, stream);
}

// Round 13
// 949.239 us; speedup vs baseline: 1.1354x; 1.1354x over previous
//
#include <hip/hip_runtime.h>
#include <hip/hip_bf16.h>

// Problem constants (Llama-ish decoder, 2 layers, prefill)
constexpr int kL = 2;
constexpr int kS = 2048;   // seq
constexpr int kH = 2048;   // hidden
constexpr int kNH = 16;    // heads
constexpr int kD = 128;    // head dim
constexpr int kI = 5632;   // intermediate

using s16x8 = __attribute__((ext_vector_type(8))) short;
using s16x4 = __attribute__((ext_vector_type(4))) short;
using f32x4 = __attribute__((ext_vector_type(4))) float;

// bf16 helpers (bf16 stored as short)
__device__ __forceinline__ float b2f(short s) {
  union { unsigned u; float f; } v;
  v.u = ((unsigned)(unsigned short)s) << 16;
  return v.f;
}
__device__ __forceinline__ short f2bs(float f) {
  __hip_bfloat16 h = __float2bfloat16(f);   // RNE
  union { __hip_bfloat16 h; short s; } u;
  u.h = h;
  return u.s;
}

// async global->LDS, 16B per lane; LDS dest is wave-uniform base + lane*16
__device__ __forceinline__ void lds16(const void* g, void* l) {
  __builtin_amdgcn_global_load_lds(
      (const __attribute__((address_space(1))) void*)g,
      (__attribute__((address_space(3))) void*)l, 16, 0, 0);
}

// 2D XCD chunking, rows-fastest within each XCD rect (r9-verified: FETCH 233->96MB)
__device__ __forceinline__ void swz_block(int gx, int& bx, int& by) {
  const int gy = gridDim.y;
  const int lin = by * gx + bx;
  if ((gx & 3) == 0 && (gy & 1) == 0) {
    const int cx = gx >> 2, cy = gy >> 1;
    const int xcd = lin & 7;
    const int s = lin >> 3;
    bx = (xcd & 3) * cx + s / cy;        // column advances slowest
    by = (xcd >> 2) * cy + s % cy;       // row advances fastest
  } else if (((gx * gy) & 7) == 0) {
    const int cpx = (gx * gy) >> 3;
    const int l2 = (lin & 7) * cpx + (lin >> 3);
    bx = l2 % gx;
    by = l2 / gx;
  }
}

// ---------------------------------------------------------------------------
// fused fp32 -> bf16 conversion of all 7 weight matrices of one layer.
// dst layout: q,k,v,o (HH each), then INTERLEAVED gate/up (row 2j = gate_j,
// row 2j+1 = up_j; 2*IH total), then d (IH).
// ---------------------------------------------------------------------------
__global__ __launch_bounds__(256) void cvt_all(const float* __restrict__ q,
                                               const float* __restrict__ k,
                                               const float* __restrict__ v,
                                               const float* __restrict__ o,
                                               const float* __restrict__ g,
                                               const float* __restrict__ u,
                                               const float* __restrict__ d,
                                               short* __restrict__ dst) {
  constexpr int HH8 = (kH * kH) / 8;       // 524288 (pow2)
  constexpr int IH8 = (kI * kH) / 8;       // 1441792
  constexpr int tot = 4 * HH8 + 3 * IH8;
  for (int i = blockIdx.x * blockDim.x + threadIdx.x; i < tot; i += gridDim.x * blockDim.x) {
    const float* src;
    int off;
    if (i < 4 * HH8) {
      const int s = i >> 19;               // / HH8
      off = i & (HH8 - 1);
      src = s == 0 ? q : s == 1 ? k : s == 2 ? v : o;
    } else {
      const int j = i - 4 * HH8;
      if (j < 2 * IH8) {                   // interleaved gate/up region
        const int r = j >> 8;              // row (2048 cols = 256 groups)
        const int c8 = j & 255;
        src = (r & 1) ? u : g;
        off = (r >> 1) * 256 + c8;
      } else {
        src = d;
        off = j - 2 * IH8;
      }
    }
    const float4 a = ((const float4*)src)[2 * off];
    const float4 b = ((const float4*)src)[2 * off + 1];
    s16x8 ov;
    ov[0] = f2bs(a.x); ov[1] = f2bs(a.y); ov[2] = f2bs(a.z); ov[3] = f2bs(a.w);
    ov[4] = f2bs(b.x); ov[5] = f2bs(b.y); ov[6] = f2bs(b.z); ov[7] = f2bs(b.w);
    ((s16x8*)dst)[i] = ov;
  }
}

// ---------------------------------------------------------------------------
// 128x128 GEMM (bf16 x bf16): C[M,N] = A[M,K] * B[N,K]^T. BK=64, 4 waves,
// double-buffered LDS (64KB, 2 blocks/CU), stage-early/compute-late, XOR
// swizzle. r8-verified __syncthreads 2-phase loop (counted-vmcnt regressed).
// EPI: 1 = fp32 residual add
//      3 = fused QKV: cols [0,2048)->C0, [2048,4096)->C1, [4096,6144)->C2^T
//      5 = fused gate+up with INTERLEAVED B rows + silu fusion:
//          col 2j = gate_j (even fr), col 2j+1 = up_j (odd fr);
//          even lanes write silu(g)*u to C0[row*5632 + col/2]
// ---------------------------------------------------------------------------
template <int EPI>
__global__ __launch_bounds__(256) void gemm_db(const short* __restrict__ A,
                                               const short* __restrict__ B,
                                               short* __restrict__ C0,
                                               short* __restrict__ C1,
                                               short* __restrict__ C2,
                                               float* __restrict__ Cf,
                                               int M, int N, int K) {
  __shared__ short As0[128 * 64], Bs0[128 * 64];
  __shared__ short As1[128 * 64], Bs1[128 * 64];
  const int t = threadIdx.x;
  const int lane = t & 63, wid = t >> 6;
  int bx = blockIdx.x, by = blockIdx.y;
  swz_block(gridDim.x, bx, by);
  const int m0 = by * 128, n0 = bx * 128;
  const int wr = (wid >> 1) * 64, wc = (wid & 1) * 64;
  const int fr = lane & 15, g4 = lane >> 4;

  const int srow = (lane >> 3);
  const int scol = (((lane & 7) << 4) ^ (srow << 4)) >> 1;  // pre-swizzled col

  f32x4 acc[4][4] = {};

  auto stage = [&](short* Ad, short* Bd, int k0) {
    #pragma unroll
    for (int c = 0; c < 4; ++c) {
      const int chunk = wid * 4 + c;
      const int e0 = chunk * 512;
      const int row = chunk * 8 + srow;
      lds16(A + (size_t)(m0 + row) * K + k0 + scol, Ad + e0);
      lds16(B + (size_t)(n0 + row) * K + k0 + scol, Bd + e0);
    }
  };

  auto compute = [&](const short* Xs, const short* Ys) {
    #pragma unroll
    for (int ks = 0; ks < 2; ++ks) {
      s16x8 a[4], b[4];
      #pragma unroll
      for (int m = 0; m < 4; ++m) {
        const int r = wr + m * 16 + fr;
        a[m] = *(const s16x8*)&Xs[r * 64 + (((ks * 4 + g4) ^ (r & 7)) << 3)];
      }
      #pragma unroll
      for (int n = 0; n < 4; ++n) {
        const int r = wc + n * 16 + fr;
        b[n] = *(const s16x8*)&Ys[r * 64 + (((ks * 4 + g4) ^ (r & 7)) << 3)];
      }
      #pragma unroll
      for (int m = 0; m < 4; ++m)
        #pragma unroll
        for (int n = 0; n < 4; ++n)
          acc[m][n] = __builtin_amdgcn_mfma_f32_16x16x32_bf16(a[m], b[n], acc[m][n], 0, 0, 0);
    }
  };

  const int nt = K >> 6;
  stage(As0, Bs0, 0);
  __syncthreads();
  for (int tt = 0; tt < nt; tt += 2) {
    stage(As1, Bs1, (tt + 1) << 6);
    compute(As0, Bs0);
    __syncthreads();
    if (tt + 2 < nt) stage(As0, Bs0, (tt + 2) << 6);
    compute(As1, Bs1);
    __syncthreads();
  }

  #pragma unroll
  for (int m = 0; m < 4; ++m) {
    #pragma unroll
    for (int n = 0; n < 4; ++n) {
      const int rb = m0 + wr + m * 16 + g4 * 4;
      const int col = n0 + wc + n * 16 + fr;
      if (EPI == 1) {
        #pragma unroll
        for (int j = 0; j < 4; ++j)
          Cf[(size_t)(rb + j) * N + col] += acc[m][n][j];
      } else if (EPI == 3) {
        const int seg = n0 >> 11;        // block-uniform
        const int cl = col - (seg << 11);
        if (seg == 0) {
          #pragma unroll
          for (int j = 0; j < 4; ++j) C0[(size_t)(rb + j) * 2048 + cl] = f2bs(acc[m][n][j]);
        } else if (seg == 1) {
          #pragma unroll
          for (int j = 0; j < 4; ++j) C1[(size_t)(rb + j) * 2048 + cl] = f2bs(acc[m][n][j]);
        } else {
          s16x4 pk;
          #pragma unroll
          for (int j = 0; j < 4; ++j) pk[j] = f2bs(acc[m][n][j]);
          *(s16x4*)&C2[(size_t)cl * M + rb] = pk;   // V^T
        }
      } else {  // EPI == 5: interleaved gate/up + fused silu
        #pragma unroll
        for (int j = 0; j < 4; ++j) {
          const float gv = acc[m][n][j];
          const float pv = __shfl_xor(gv, 1);   // partner column (fr^1)
          if ((fr & 1) == 0) {                  // gate lane: gv=gate, pv=up
            const float s = gv / (1.f + __expf(-gv));
            C0[(size_t)(rb + j) * kI + (col >> 1)] = f2bs(s * pv);
          }
        }
      }
    }
  }
}

// ---------------------------------------------------------------------------
// Fallback GEMM (bf16 A x fp32 B) — used only if workspace too small.
// ---------------------------------------------------------------------------
template <int EPI>
__global__ __launch_bounds__(256) void gemm_btf(const short* __restrict__ A,
                                                const float* __restrict__ B,
                                                short* __restrict__ Cb,
                                                float* __restrict__ Cf,
                                                int M, int N, int K) {
  __shared__ short As[128 * 32];
  __shared__ short Bs[128 * 32];
  const int t = threadIdx.x;
  const int lane = t & 63, wid = t >> 6;
  int bx = blockIdx.x, by = blockIdx.y;
  swz_block(gridDim.x, bx, by);
  const int m0 = by * 128, n0 = bx * 128;
  const int wr = (wid >> 1) * 64, wc = (wid & 1) * 64;
  const int fr = lane & 15, h8 = (lane >> 4) * 8;
  const int brow = t >> 1, bcol = (t & 1) * 16;
  const float* bsrc = B + (size_t)(n0 + brow) * K + bcol;

  f32x4 acc[4][4] = {};

  for (int k0 = 0; k0 < K; k0 += 32) {
    const float4 bv0 = *(const float4*)(bsrc + k0);
    const float4 bv1 = *(const float4*)(bsrc + k0 + 4);
    const float4 bv2 = *(const float4*)(bsrc + k0 + 8);
    const float4 bv3 = *(const float4*)(bsrc + k0 + 12);
    __syncthreads();
    {
      const float bf[16] = {bv0.x, bv0.y, bv0.z, bv0.w, bv1.x, bv1.y, bv1.z, bv1.w,
                            bv2.x, bv2.y, bv2.z, bv2.w, bv3.x, bv3.y, bv3.z, bv3.w};
      s16x8 wlo, whi;
      #pragma unroll
      for (int j = 0; j < 8; ++j) { wlo[j] = f2bs(bf[j]); whi[j] = f2bs(bf[8 + j]); }
      *(s16x8*)&Bs[brow * 32 + bcol] = wlo;
      *(s16x8*)&Bs[brow * 32 + bcol + 8] = whi;
    }
    #pragma unroll
    for (int c = 0; c < 2; ++c) {
      const int e0 = c * 2048 + wid * 512;
      const int e = e0 + lane * 8;
      const int row = e >> 5, col = e & 31;
      lds16(A + (size_t)(m0 + row) * K + k0 + col, (void*)(As + e0));
    }
    __syncthreads();

    s16x8 a[4], b[4];
    #pragma unroll
    for (int m = 0; m < 4; ++m) a[m] = *(const s16x8*)&As[(wr + m * 16 + fr) * 32 + h8];
    #pragma unroll
    for (int n = 0; n < 4; ++n) b[n] = *(const s16x8*)&Bs[(wc + n * 16 + fr) * 32 + h8];
    #pragma unroll
    for (int m = 0; m < 4; ++m)
      #pragma unroll
      for (int n = 0; n < 4; ++n)
        acc[m][n] = __builtin_amdgcn_mfma_f32_16x16x32_bf16(a[m], b[n], acc[m][n], 0, 0, 0);
  }

  const int g4 = lane >> 4;
  #pragma unroll
  for (int m = 0; m < 4; ++m) {
    #pragma unroll
    for (int n = 0; n < 4; ++n) {
      const int rb = m0 + wr + m * 16 + g4 * 4;
      const int col = n0 + wc + n * 16 + fr;
      if (EPI == 0) {
        #pragma unroll
        for (int j = 0; j < 4; ++j)
          Cb[(size_t)(rb + j) * N + col] = f2bs(acc[m][n][j]);
      } else if (EPI == 1) {
        #pragma unroll
        for (int j = 0; j < 4; ++j)
          Cf[(size_t)(rb + j) * N + col] += acc[m][n][j];
      } else {
        s16x4 pk;
        #pragma unroll
        for (int j = 0; j < 4; ++j) pk[j] = f2bs(acc[m][n][j]);
        *(s16x4*)&Cb[(size_t)col * M + rb] = pk;
      }
    }
  }
}

// ---------------------------------------------------------------------------
// RMSNorm: h = x / sqrt(mean(x^2)+eps) * w   (x fp32, w fp32, h bf16)
// ---------------------------------------------------------------------------
__global__ __launch_bounds__(256) void rmsnorm_k(const float* __restrict__ x,
                                                 const float* __restrict__ w,
                                                 short* __restrict__ h) {
  const int row = blockIdx.x, t = threadIdx.x;
  const float4* xr = (const float4*)(x + (size_t)row * kH);
  const float4 v0 = xr[2 * t], v1 = xr[2 * t + 1];
  float ss = v0.x * v0.x + v0.y * v0.y + v0.z * v0.z + v0.w * v0.w +
             v1.x * v1.x + v1.y * v1.y + v1.z * v1.z + v1.w * v1.w;
  #pragma unroll
  for (int off = 1; off < 64; off <<= 1) ss += __shfl_xor(ss, off);
  __shared__ float red[4];
  if ((t & 63) == 0) red[t >> 6] = ss;
  __syncthreads();
  ss = red[0] + red[1] + red[2] + red[3];
  const float rs = rsqrtf(ss * (1.0f / kH) + 1e-6f);
  const float4 w0 = ((const float4*)w)[2 * t];
  const float4 w1 = ((const float4*)w)[2 * t + 1];
  const float xv[8] = {v0.x, v0.y, v0.z, v0.w, v1.x, v1.y, v1.z, v1.w};
  const float wv[8] = {w0.x, w0.y, w0.z, w0.w, w1.x, w1.y, w1.z, w1.w};
  s16x8 o;
  #pragma unroll
  for (int j = 0; j < 8; ++j) o[j] = f2bs(xv[j] * rs * wv[j]);
  *(s16x8*)&h[(size_t)row * kH + t * 8] = o;
}

// ---------------------------------------------------------------------------
// RoPE in-place on q and k (bf16). cos/sin fp32 tables repeat halves.
// ---------------------------------------------------------------------------
__global__ __launch_bounds__(256) void rope_k(short* __restrict__ q, short* __restrict__ k,
                                              const float* __restrict__ cosb,
                                              const float* __restrict__ sinb,
                                              const int* __restrict__ pos) {
  const int s = blockIdx.x;
  const int p = pos[s];
  const size_t rowb = (size_t)s * kH;
  for (int idx = threadIdx.x; idx < kNH * 64; idx += 256) {
    const int hh = idx >> 6, d = idx & 63;
    const float c = cosb[p * kD + d];
    const float sn = sinb[p * kD + d];
    const size_t i1 = rowb + hh * kD + d, i2 = i1 + 64;
    const float q1 = b2f(q[i1]), q2 = b2f(q[i2]);
    q[i1] = f2bs(q1 * c - q2 * sn);
    q[i2] = f2bs(q2 * c + q1 * sn);
    const float k1 = b2f(k[i1]), k2 = b2f(k[i2]);
    k[i1] = f2bs(k1 * c - k2 * sn);
    k[i2] = f2bs(k2 * c + k1 * sn);
  }
}

// ---------------------------------------------------------------------------
// Flash attention, causal. Block = (head, 64-row Q tile), 4 waves x 16 rows.
// K/V double-buffered in LDS; T14 async-STAGE; one barrier per KV-step.
// ---------------------------------------------------------------------------
__global__ __launch_bounds__(256) void attn_k(const short* __restrict__ q,
                                              const short* __restrict__ k,
                                              const short* __restrict__ vt,
                                              short* __restrict__ o) {
  __shared__ short Kl[2][64 * 128];
  __shared__ short Vl[2][128 * 64];
  __shared__ short Pl[4][16 * 72];
  const int h = blockIdx.x;
  const int y = blockIdx.y;
  const int qi = (y < 16) ? y : 47 - y;    // balanced pairing
  const int t = threadIdx.x;
  const int lane = t & 63, wid = t >> 6;
  const int fr = lane & 15, g4 = lane >> 4;
  const int q0 = qi * 64 + wid * 16;

  s16x8 aq[4];
  {
    const short* qp = q + (size_t)(q0 + fr) * kH + h * kD;
    #pragma unroll
    for (int ks = 0; ks < 4; ++ks) aq[ks] = *(const s16x8*)(qp + ks * 32 + g4 * 8);
  }
  f32x4 acco[8] = {};
  float mrun[4], lrun[4];
  #pragma unroll
  for (int j = 0; j < 4; ++j) { mrun[j] = -3.0e30f; lrun[j] = 0.f; }

  s16x8 kreg[4], vreg[4];
  auto loadt = [&](int tt) {
    const int kv0 = tt * 64;
    #pragma unroll
    for (int c = 0; c < 4; ++c) {
      const int b = c * 4096 + t * 16;
      kreg[c] = *(const s16x8*)(k + (size_t)(kv0 + (b >> 8)) * kH + h * kD + ((b & 255) >> 1));
      vreg[c] = *(const s16x8*)(vt + (size_t)(h * kD + (b >> 7)) * kS + kv0 + ((b & 127) >> 1));
    }
  };
  auto writet = [&](int buf) {
    #pragma unroll
    for (int c = 0; c < 4; ++c) {
      const int b = c * 4096 + t * 16;
      const int kr = b >> 8, kc = b & 255;
      *(s16x8*)((char*)Kl[buf] + kr * 256 + (kc ^ ((kr & 7) << 4))) = kreg[c];
      const int vr = b >> 7, vc = b & 127;
      *(s16x8*)((char*)Vl[buf] + vr * 128 + (vc ^ ((vr & 7) << 4))) = vreg[c];
    }
  };

  loadt(0);
  writet(0);
  __syncthreads();

  for (int tt = 0; tt <= qi; ++tt) {
    const int kv0 = tt * 64;
    const int cur = tt & 1;
    if (tt < qi) loadt(tt + 1);            // issue early; lands during compute

    // QK^T : 16 q-rows x 64 kv
    f32x4 sc[4] = {};
    __builtin_amdgcn_s_setprio(1);
    #pragma unroll
    for (int ks = 0; ks < 4; ++ks) {
      const int ch16 = ks * 4 + g4;
      #pragma unroll
      for (int nf = 0; nf < 4; ++nf) {
        const int row = nf * 16 + fr;
        const s16x8 bk =
            *(const s16x8*)((const char*)Kl[cur] + row * 256 + ((ch16 ^ (row & 7)) << 4));
        sc[nf] = __builtin_amdgcn_mfma_f32_16x16x32_bf16(aq[ks], bk, sc[nf], 0, 0, 0);
      }
    }
    __builtin_amdgcn_s_setprio(0);

    float val[4][4];
    #pragma unroll
    for (int nf = 0; nf < 4; ++nf) {
      #pragma unroll
      for (int j = 0; j < 4; ++j) {
        float v = sc[nf][j] * 0.08838834764831845f;
        if (tt == qi) {
          const int colg = kv0 + nf * 16 + fr;
          const int rowg = q0 + g4 * 4 + j;
          if (colg > rowg) v -= 1.0e9f;
        }
        val[nf][j] = v;
      }
    }

    #pragma unroll
    for (int j = 0; j < 4; ++j) {
      float rm = fmaxf(fmaxf(val[0][j], val[1][j]), fmaxf(val[2][j], val[3][j]));
      rm = fmaxf(rm, __shfl_xor(rm, 1));
      rm = fmaxf(rm, __shfl_xor(rm, 2));
      rm = fmaxf(rm, __shfl_xor(rm, 4));
      rm = fmaxf(rm, __shfl_xor(rm, 8));
      const float mnew = fmaxf(mrun[j], rm);
      const float corr = __expf(mrun[j] - mnew);
      mrun[j] = mnew;
      float ps = 0.f;
      #pragma unroll
      for (int nf = 0; nf < 4; ++nf) {
        const float p = __expf(val[nf][j] - mnew);
        ps += p;
        Pl[wid][(g4 * 4 + j) * 72 + nf * 16 + fr] = f2bs(p);
      }
      ps += __shfl_xor(ps, 1);
      ps += __shfl_xor(ps, 2);
      ps += __shfl_xor(ps, 4);
      ps += __shfl_xor(ps, 8);
      lrun[j] = lrun[j] * corr + ps;
      #pragma unroll
      for (int nf = 0; nf < 8; ++nf) acco[nf][j] *= corr;
    }

    // PV: P(16x64) @ V(64x128)
    __builtin_amdgcn_s_setprio(1);
    #pragma unroll
    for (int ks = 0; ks < 2; ++ks) {
      const s16x8 ap = *(const s16x8*)(&Pl[wid][fr * 72 + ks * 32 + g4 * 8]);
      const int ch16 = ks * 4 + g4;
      #pragma unroll
      for (int nf = 0; nf < 8; ++nf) {
        const int dd = nf * 16 + fr;
        const s16x8 bv =
            *(const s16x8*)((const char*)Vl[cur] + dd * 128 + ((ch16 ^ (dd & 7)) << 4));
        acco[nf] = __builtin_amdgcn_mfma_f32_16x16x32_bf16(ap, bv, acco[nf], 0, 0, 0);
      }
    }
    __builtin_amdgcn_s_setprio(0);

    if (tt < qi) writet(cur ^ 1);          // write-late into the other buffer
    __syncthreads();                       // single barrier per KV-step
  }

  #pragma unroll
  for (int nf = 0; nf < 8; ++nf) {
    #pragma unroll
    for (int j = 0; j < 4; ++j) {
      const int rowg = q0 + g4 * 4 + j;
      o[(size_t)rowg * kH + h * kD + nf * 16 + fr] = f2bs(acco[nf][j] / lrun[j]);
    }
  }
}

// ---------------------------------------------------------------------------
// silu(gate) * up, in place into g (bf16) — fallback path only
// ---------------------------------------------------------------------------
__global__ void silu_mul(short* __restrict__ g, const short* __restrict__ u, int n8) {
  for (int i = blockIdx.x * blockDim.x + threadIdx.x; i < n8; i += gridDim.x * blockDim.x) {
    const s16x8 gv = ((const s16x8*)g)[i];
    const s16x8 uv = ((const s16x8*)u)[i];
    s16x8 o;
    #pragma unroll
    for (int j = 0; j < 8; ++j) {
      const float gf = b2f(gv[j]);
      const float s = gf / (1.f + __expf(-gf));
      o[j] = f2bs(s * b2f(uv[j]));
    }
    ((s16x8*)g)[i] = o;
  }
}

// ---------------------------------------------------------------------------
extern "C" void kernel_launch(void* const* d_in, const int* in_sizes, int n_in,
                              void* d_out, int out_size, void* d_ws, size_t ws_size,
                              hipStream_t stream) {
  (void)in_sizes; (void)n_in; (void)out_size;
  const float* hidden = (const float*)d_in[0];
  const float* cosb = (const float*)d_in[2];
  const float* sinb = (const float*)d_in[3];
  const float* wq = (const float*)d_in[4];
  const float* wk = (const float*)d_in[5];
  const float* wv = (const float*)d_in[6];
  const float* wo = (const float*)d_in[7];
  const float* wg = (const float*)d_in[8];
  const float* wu = (const float*)d_in[9];
  const float* wd = (const float*)d_in[10];
  const float* ln1 = (const float*)d_in[11];
  const float* ln2 = (const float*)d_in[12];
  const int* pos = (const int*)d_in[13];
  float* out = (float*)d_out;

  // workspace layout
  char* p = (char*)d_ws;
  float* x  = (float*)p;  p += (size_t)kS * kH * 4;   // fp32 residual (16.8MB)
  short* hb = (short*)p;  p += (size_t)kS * kH * 2;   // normed acts (8.4MB)
  char* U = p;            p += (size_t)kS * kI * 4;   // union region (46.1MB)
  short* qb = (short*)(U);
  short* kb = (short*)(U + (size_t)kS * kH * 2);
  short* vtb = (short*)(U + (size_t)kS * kH * 4);     // V^T [H][S]
  short* ob = (short*)(U + (size_t)kS * kH * 6);      // attention out
  short* gb = (short*)(U);                            // act = silu(g)*u (MLP)
  short* ub = (short*)(U + (size_t)kS * kI * 2);      // up (fallback only)
  short* wbuf = (short*)p;                            // bf16 weights, one layer
  const size_t nHH = (size_t)kH * kH, nIH = (size_t)kI * kH;
  const size_t need = (size_t)(p - (char*)d_ws) + (4 * nHH + 3 * nIH) * 2;
  const bool pre = ws_size >= need;

  short* wqb = wbuf;            // q,k,v contiguous -> fused N=6144 B matrix
  short* wob = wqb + 3 * nHH;
  short* wgu = wob + nHH;       // INTERLEAVED gate/up -> N=11264 B matrix
  short* wdb = wgu + 2 * nIH;

  hipMemcpyAsync(x, hidden, (size_t)kS * kH * 4, hipMemcpyDeviceToDevice, stream);
  for (int l = 0; l < kL; ++l) {
    rmsnorm_k<<<kS, 256, 0, stream>>>(x, ln1 + (size_t)l * kH, hb);
    if (pre) {
      cvt_all<<<2048, 256, 0, stream>>>(wq + l * nHH, wk + l * nHH, wv + l * nHH,
                                        wo + l * nHH, wg + l * nIH, wu + l * nIH,
                                        wd + l * nIH, wbuf);
      // fused QKV: N = 6144 (grid 48x16 -> XCD rects 12x8)
      gemm_db<3><<<dim3(6144 / 128, kS / 128), 256, 0, stream>>>(
          hb, wqb, qb, kb, vtb, nullptr, kS, 6144, kH);
      rope_k<<<kS, 256, 0, stream>>>(qb, kb, cosb, sinb, pos);
      attn_k<<<dim3(kNH, kS / 64), 256, 0, stream>>>(qb, kb, vtb, ob);
      gemm_db<1><<<dim3(kH / 128, kS / 128), 256, 0, stream>>>(
          ob, wob, nullptr, nullptr, nullptr, x, kS, kH, kH);
      rmsnorm_k<<<kS, 256, 0, stream>>>(x, ln2 + (size_t)l * kH, hb);
      // fused gate+up+silu: N = 11264 interleaved (grid 88x16), writes act
      gemm_db<5><<<dim3(11264 / 128, kS / 128), 256, 0, stream>>>(
          hb, wgu, gb, nullptr, nullptr, nullptr, kS, 11264, kH);
      gemm_db<1><<<dim3(kH / 128, kS / 128), 256, 0, stream>>>(
          gb, wdb, nullptr, nullptr, nullptr, x, kS, kH, kI);
    } else {
      gemm_btf<0><<<dim3(kH / 128, kS / 128), 256, 0, stream>>>(hb, wq + l * nHH, qb, nullptr, kS, kH, kH);
      gemm_btf<0><<<dim3(kH / 128, kS / 128), 256, 0, stream>>>(hb, wk + l * nHH, kb, nullptr, kS, kH, kH);
      gemm_btf<2><<<dim3(kH / 128, kS / 128), 256, 0, stream>>>(hb, wv + l * nHH, vtb, nullptr, kS, kH, kH);
      rope_k<<<kS, 256, 0, stream>>>(qb, kb, cosb, sinb, pos);
      attn_k<<<dim3(kNH, kS / 64), 256, 0, stream>>>(qb, kb, vtb, ob);
      gemm_btf<1><<<dim3(kH / 128, kS / 128), 256, 0, stream>>>(ob, wo + l * nHH, nullptr, x, kS, kH, kH);
      rmsnorm_k<<<kS, 256, 0, stream>>>(x, ln2 + (size_t)l * kH, hb);
      gemm_btf<0><<<dim3(kI / 128, kS / 128), 256, 0, stream>>>(hb, wg + l * nIH, gb, nullptr, kS, kI, kH);
      gemm_btf<0><<<dim3(kI / 128, kS / 128), 256, 0, stream>>>(hb, wu + l * nIH, ub, nullptr, kS, kI, kH);
      silu_mul<<<1408, 256, 0, stream>>>(gb, ub, kS * kI / 8);
      gemm_btf<1><<<dim3(kH / 128, kS / 128), 256, 0, stream>>>(gb, wd + l * nIH, nullptr, x, kS, kH, kI);
    }
  }
  hipMemcpyAsync(out, x, (size_t)kS * kH * 4, hipMemcpyDeviceToDevice, stream);
}

// Round 14
// 901.733 us; speedup vs baseline: 1.1953x; 1.0527x over previous
//
#include <hip/hip_runtime.h>
#include <hip/hip_bf16.h>

// Problem constants (Llama-ish decoder, 2 layers, prefill)
constexpr int kL = 2;
constexpr int kS = 2048;   // seq
constexpr int kH = 2048;   // hidden
constexpr int kNH = 16;    // heads
constexpr int kD = 128;    // head dim
constexpr int kI = 5632;   // intermediate

using s16x8 = __attribute__((ext_vector_type(8))) short;
using s16x4 = __attribute__((ext_vector_type(4))) short;
using f32x4 = __attribute__((ext_vector_type(4))) float;

// bf16 helpers (bf16 stored as short)
__device__ __forceinline__ float b2f(short s) {
  union { unsigned u; float f; } v;
  v.u = ((unsigned)(unsigned short)s) << 16;
  return v.f;
}
__device__ __forceinline__ short f2bs(float f) {
  __hip_bfloat16 h = __float2bfloat16(f);   // RNE
  union { __hip_bfloat16 h; short s; } u;
  u.h = h;
  return u.s;
}

// async global->LDS, 16B per lane; LDS dest is wave-uniform base + lane*16
__device__ __forceinline__ void lds16(const void* g, void* l) {
  __builtin_amdgcn_global_load_lds(
      (const __attribute__((address_space(1))) void*)g,
      (__attribute__((address_space(3))) void*)l, 16, 0, 0);
}

// 2D XCD chunking, rows-fastest within each XCD rect (r9-verified: FETCH 233->96MB)
__device__ __forceinline__ void swz_block(int gx, int& bx, int& by) {
  const int gy = gridDim.y;
  const int lin = by * gx + bx;
  if ((gx & 3) == 0 && (gy & 1) == 0) {
    const int cx = gx >> 2, cy = gy >> 1;
    const int xcd = lin & 7;
    const int s = lin >> 3;
    bx = (xcd & 3) * cx + s / cy;        // column advances slowest
    by = (xcd >> 2) * cy + s % cy;       // row advances fastest
  } else if (((gx * gy) & 7) == 0) {
    const int cpx = (gx * gy) >> 3;
    const int l2 = (lin & 7) * cpx + (lin >> 3);
    bx = l2 % gx;
    by = l2 / gx;
  }
}

// ---------------------------------------------------------------------------
// fused fp32 -> bf16 conversion of all 7 weight matrices of one layer.
// dst layout: q,k,v,o (HH each), then INTERLEAVED gate/up (row 2j = gate_j,
// row 2j+1 = up_j; 2*IH total), then d (IH).
// ---------------------------------------------------------------------------
__global__ __launch_bounds__(256) void cvt_all(const float* __restrict__ q,
                                               const float* __restrict__ k,
                                               const float* __restrict__ v,
                                               const float* __restrict__ o,
                                               const float* __restrict__ g,
                                               const float* __restrict__ u,
                                               const float* __restrict__ d,
                                               short* __restrict__ dst) {
  constexpr int HH8 = (kH * kH) / 8;       // 524288 (pow2)
  constexpr int IH8 = (kI * kH) / 8;       // 1441792
  constexpr int tot = 4 * HH8 + 3 * IH8;
  for (int i = blockIdx.x * blockDim.x + threadIdx.x; i < tot; i += gridDim.x * blockDim.x) {
    const float* src;
    int off;
    if (i < 4 * HH8) {
      const int s = i >> 19;               // / HH8
      off = i & (HH8 - 1);
      src = s == 0 ? q : s == 1 ? k : s == 2 ? v : o;
    } else {
      const int j = i - 4 * HH8;
      if (j < 2 * IH8) {                   // interleaved gate/up region
        const int r = j >> 8;              // row (2048 cols = 256 groups)
        const int c8 = j & 255;
        src = (r & 1) ? u : g;
        off = (r >> 1) * 256 + c8;
      } else {
        src = d;
        off = j - 2 * IH8;
      }
    }
    const float4 a = ((const float4*)src)[2 * off];
    const float4 b = ((const float4*)src)[2 * off + 1];
    s16x8 ov;
    ov[0] = f2bs(a.x); ov[1] = f2bs(a.y); ov[2] = f2bs(a.z); ov[3] = f2bs(a.w);
    ov[4] = f2bs(b.x); ov[5] = f2bs(b.y); ov[6] = f2bs(b.z); ov[7] = f2bs(b.w);
    ((s16x8*)dst)[i] = ov;
  }
}

// ---------------------------------------------------------------------------
// 128x128 GEMM (bf16 x bf16): C[M,N] = A[M,K] * B[N,K]^T. BK=64, 4 waves,
// double-buffered LDS (64KB, 2 blocks/CU), stage-early/compute-late, XOR
// swizzle. Optional K-split via gridDim.z (each z-slice does K/gridDim.z).
// EPI: 1 = fp32 residual add (gridDim.z==1 only)
//      3 = fused QKV: cols [0,2048)->C0, [2048,4096)->C1, [4096,6144)->C2^T
//      5 = fused gate+up interleaved + silu
//      6 = fp32 residual atomic add (for split-K; unsafeAtomicAdd = native f32)
// ---------------------------------------------------------------------------
template <int EPI>
__global__ __launch_bounds__(256) void gemm_db(const short* __restrict__ A,
                                               const short* __restrict__ B,
                                               short* __restrict__ C0,
                                               short* __restrict__ C1,
                                               short* __restrict__ C2,
                                               float* __restrict__ Cf,
                                               int M, int N, int K) {
  __shared__ short As0[128 * 64], Bs0[128 * 64];
  __shared__ short As1[128 * 64], Bs1[128 * 64];
  const int t = threadIdx.x;
  const int lane = t & 63, wid = t >> 6;
  int bx = blockIdx.x, by = blockIdx.y;
  swz_block(gridDim.x, bx, by);
  const int m0 = by * 128, n0 = bx * 128;
  const int Ksub = K / (int)gridDim.z;
  const int kbase = blockIdx.z * Ksub;
  const int wr = (wid >> 1) * 64, wc = (wid & 1) * 64;
  const int fr = lane & 15, g4 = lane >> 4;

  const int srow = (lane >> 3);
  const int scol = (((lane & 7) << 4) ^ (srow << 4)) >> 1;  // pre-swizzled col

  f32x4 acc[4][4] = {};

  auto stage = [&](short* Ad, short* Bd, int k0) {
    #pragma unroll
    for (int c = 0; c < 4; ++c) {
      const int chunk = wid * 4 + c;
      const int e0 = chunk * 512;
      const int row = chunk * 8 + srow;
      lds16(A + (size_t)(m0 + row) * K + kbase + k0 + scol, Ad + e0);
      lds16(B + (size_t)(n0 + row) * K + kbase + k0 + scol, Bd + e0);
    }
  };

  auto compute = [&](const short* Xs, const short* Ys) {
    #pragma unroll
    for (int ks = 0; ks < 2; ++ks) {
      s16x8 a[4], b[4];
      #pragma unroll
      for (int m = 0; m < 4; ++m) {
        const int r = wr + m * 16 + fr;
        a[m] = *(const s16x8*)&Xs[r * 64 + (((ks * 4 + g4) ^ (r & 7)) << 3)];
      }
      #pragma unroll
      for (int n = 0; n < 4; ++n) {
        const int r = wc + n * 16 + fr;
        b[n] = *(const s16x8*)&Ys[r * 64 + (((ks * 4 + g4) ^ (r & 7)) << 3)];
      }
      #pragma unroll
      for (int m = 0; m < 4; ++m)
        #pragma unroll
        for (int n = 0; n < 4; ++n)
          acc[m][n] = __builtin_amdgcn_mfma_f32_16x16x32_bf16(a[m], b[n], acc[m][n], 0, 0, 0);
    }
  };

  const int nt = Ksub >> 6;              // even for all our shapes (16/32/44/88)
  stage(As0, Bs0, 0);
  __syncthreads();
  for (int tt = 0; tt < nt; tt += 2) {
    stage(As1, Bs1, (tt + 1) << 6);
    compute(As0, Bs0);
    __syncthreads();
    if (tt + 2 < nt) stage(As0, Bs0, (tt + 2) << 6);
    compute(As1, Bs1);
    __syncthreads();
  }

  #pragma unroll
  for (int m = 0; m < 4; ++m) {
    #pragma unroll
    for (int n = 0; n < 4; ++n) {
      const int rb = m0 + wr + m * 16 + g4 * 4;
      const int col = n0 + wc + n * 16 + fr;
      if (EPI == 1) {
        #pragma unroll
        for (int j = 0; j < 4; ++j)
          Cf[(size_t)(rb + j) * N + col] += acc[m][n][j];
      } else if (EPI == 6) {
        #pragma unroll
        for (int j = 0; j < 4; ++j)
          unsafeAtomicAdd(&Cf[(size_t)(rb + j) * N + col], acc[m][n][j]);
      } else if (EPI == 3) {
        const int seg = n0 >> 11;        // block-uniform
        const int cl = col - (seg << 11);
        if (seg == 0) {
          #pragma unroll
          for (int j = 0; j < 4; ++j) C0[(size_t)(rb + j) * 2048 + cl] = f2bs(acc[m][n][j]);
        } else if (seg == 1) {
          #pragma unroll
          for (int j = 0; j < 4; ++j) C1[(size_t)(rb + j) * 2048 + cl] = f2bs(acc[m][n][j]);
        } else {
          s16x4 pk;
          #pragma unroll
          for (int j = 0; j < 4; ++j) pk[j] = f2bs(acc[m][n][j]);
          *(s16x4*)&C2[(size_t)cl * M + rb] = pk;   // V^T
        }
      } else {  // EPI == 5: interleaved gate/up + fused silu
        #pragma unroll
        for (int j = 0; j < 4; ++j) {
          const float gv = acc[m][n][j];
          const float pv = __shfl_xor(gv, 1);   // partner column (fr^1)
          if ((fr & 1) == 0) {                  // gate lane: gv=gate, pv=up
            const float s = gv / (1.f + __expf(-gv));
            C0[(size_t)(rb + j) * kI + (col >> 1)] = f2bs(s * pv);
          }
        }
      }
    }
  }
}

// ---------------------------------------------------------------------------
// Fallback GEMM (bf16 A x fp32 B) — used only if workspace too small.
// ---------------------------------------------------------------------------
template <int EPI>
__global__ __launch_bounds__(256) void gemm_btf(const short* __restrict__ A,
                                                const float* __restrict__ B,
                                                short* __restrict__ Cb,
                                                float* __restrict__ Cf,
                                                int M, int N, int K) {
  __shared__ short As[128 * 32];
  __shared__ short Bs[128 * 32];
  const int t = threadIdx.x;
  const int lane = t & 63, wid = t >> 6;
  int bx = blockIdx.x, by = blockIdx.y;
  swz_block(gridDim.x, bx, by);
  const int m0 = by * 128, n0 = bx * 128;
  const int wr = (wid >> 1) * 64, wc = (wid & 1) * 64;
  const int fr = lane & 15, h8 = (lane >> 4) * 8;
  const int brow = t >> 1, bcol = (t & 1) * 16;
  const float* bsrc = B + (size_t)(n0 + brow) * K + bcol;

  f32x4 acc[4][4] = {};

  for (int k0 = 0; k0 < K; k0 += 32) {
    const float4 bv0 = *(const float4*)(bsrc + k0);
    const float4 bv1 = *(const float4*)(bsrc + k0 + 4);
    const float4 bv2 = *(const float4*)(bsrc + k0 + 8);
    const float4 bv3 = *(const float4*)(bsrc + k0 + 12);
    __syncthreads();
    {
      const float bf[16] = {bv0.x, bv0.y, bv0.z, bv0.w, bv1.x, bv1.y, bv1.z, bv1.w,
                            bv2.x, bv2.y, bv2.z, bv2.w, bv3.x, bv3.y, bv3.z, bv3.w};
      s16x8 wlo, whi;
      #pragma unroll
      for (int j = 0; j < 8; ++j) { wlo[j] = f2bs(bf[j]); whi[j] = f2bs(bf[8 + j]); }
      *(s16x8*)&Bs[brow * 32 + bcol] = wlo;
      *(s16x8*)&Bs[brow * 32 + bcol + 8] = whi;
    }
    #pragma unroll
    for (int c = 0; c < 2; ++c) {
      const int e0 = c * 2048 + wid * 512;
      const int e = e0 + lane * 8;
      const int row = e >> 5, col = e & 31;
      lds16(A + (size_t)(m0 + row) * K + k0 + col, (void*)(As + e0));
    }
    __syncthreads();

    s16x8 a[4], b[4];
    #pragma unroll
    for (int m = 0; m < 4; ++m) a[m] = *(const s16x8*)&As[(wr + m * 16 + fr) * 32 + h8];
    #pragma unroll
    for (int n = 0; n < 4; ++n) b[n] = *(const s16x8*)&Bs[(wc + n * 16 + fr) * 32 + h8];
    #pragma unroll
    for (int m = 0; m < 4; ++m)
      #pragma unroll
      for (int n = 0; n < 4; ++n)
        acc[m][n] = __builtin_amdgcn_mfma_f32_16x16x32_bf16(a[m], b[n], acc[m][n], 0, 0, 0);
  }

  const int g4 = lane >> 4;
  #pragma unroll
  for (int m = 0; m < 4; ++m) {
    #pragma unroll
    for (int n = 0; n < 4; ++n) {
      const int rb = m0 + wr + m * 16 + g4 * 4;
      const int col = n0 + wc + n * 16 + fr;
      if (EPI == 0) {
        #pragma unroll
        for (int j = 0; j < 4; ++j)
          Cb[(size_t)(rb + j) * N + col] = f2bs(acc[m][n][j]);
      } else if (EPI == 1) {
        #pragma unroll
        for (int j = 0; j < 4; ++j)
          Cf[(size_t)(rb + j) * N + col] += acc[m][n][j];
      } else {
        s16x4 pk;
        #pragma unroll
        for (int j = 0; j < 4; ++j) pk[j] = f2bs(acc[m][n][j]);
        *(s16x4*)&Cb[(size_t)col * M + rb] = pk;
      }
    }
  }
}

// ---------------------------------------------------------------------------
// RMSNorm: h = x / sqrt(mean(x^2)+eps) * w   (x fp32, w fp32, h bf16)
// ---------------------------------------------------------------------------
__global__ __launch_bounds__(256) void rmsnorm_k(const float* __restrict__ x,
                                                 const float* __restrict__ w,
                                                 short* __restrict__ h) {
  const int row = blockIdx.x, t = threadIdx.x;
  const float4* xr = (const float4*)(x + (size_t)row * kH);
  const float4 v0 = xr[2 * t], v1 = xr[2 * t + 1];
  float ss = v0.x * v0.x + v0.y * v0.y + v0.z * v0.z + v0.w * v0.w +
             v1.x * v1.x + v1.y * v1.y + v1.z * v1.z + v1.w * v1.w;
  #pragma unroll
  for (int off = 1; off < 64; off <<= 1) ss += __shfl_xor(ss, off);
  __shared__ float red[4];
  if ((t & 63) == 0) red[t >> 6] = ss;
  __syncthreads();
  ss = red[0] + red[1] + red[2] + red[3];
  const float rs = rsqrtf(ss * (1.0f / kH) + 1e-6f);
  const float4 w0 = ((const float4*)w)[2 * t];
  const float4 w1 = ((const float4*)w)[2 * t + 1];
  const float xv[8] = {v0.x, v0.y, v0.z, v0.w, v1.x, v1.y, v1.z, v1.w};
  const float wv[8] = {w0.x, w0.y, w0.z, w0.w, w1.x, w1.y, w1.z, w1.w};
  s16x8 o;
  #pragma unroll
  for (int j = 0; j < 8; ++j) o[j] = f2bs(xv[j] * rs * wv[j]);
  *(s16x8*)&h[(size_t)row * kH + t * 8] = o;
}

// ---------------------------------------------------------------------------
// RoPE in-place on q and k (bf16). cos/sin fp32 tables repeat halves.
// ---------------------------------------------------------------------------
__global__ __launch_bounds__(256) void rope_k(short* __restrict__ q, short* __restrict__ k,
                                              const float* __restrict__ cosb,
                                              const float* __restrict__ sinb,
                                              const int* __restrict__ pos) {
  const int s = blockIdx.x;
  const int p = pos[s];
  const size_t rowb = (size_t)s * kH;
  for (int idx = threadIdx.x; idx < kNH * 64; idx += 256) {
    const int hh = idx >> 6, d = idx & 63;
    const float c = cosb[p * kD + d];
    const float sn = sinb[p * kD + d];
    const size_t i1 = rowb + hh * kD + d, i2 = i1 + 64;
    const float q1 = b2f(q[i1]), q2 = b2f(q[i2]);
    q[i1] = f2bs(q1 * c - q2 * sn);
    q[i2] = f2bs(q2 * c + q1 * sn);
    const float k1 = b2f(k[i1]), k2 = b2f(k[i2]);
    k[i1] = f2bs(k1 * c - k2 * sn);
    k[i2] = f2bs(k2 * c + k1 * sn);
  }
}

// ---------------------------------------------------------------------------
// Flash attention, causal. Block = (head, 64-row Q tile), 4 waves x 16 rows.
// K/V double-buffered in LDS; T14 async-STAGE; one barrier per KV-step.
// ---------------------------------------------------------------------------
__global__ __launch_bounds__(256) void attn_k(const short* __restrict__ q,
                                              const short* __restrict__ k,
                                              const short* __restrict__ vt,
                                              short* __restrict__ o) {
  __shared__ short Kl[2][64 * 128];
  __shared__ short Vl[2][128 * 64];
  __shared__ short Pl[4][16 * 72];
  const int h = blockIdx.x;
  const int y = blockIdx.y;
  const int qi = (y < 16) ? y : 47 - y;    // balanced pairing
  const int t = threadIdx.x;
  const int lane = t & 63, wid = t >> 6;
  const int fr = lane & 15, g4 = lane >> 4;
  const int q0 = qi * 64 + wid * 16;

  s16x8 aq[4];
  {
    const short* qp = q + (size_t)(q0 + fr) * kH + h * kD;
    #pragma unroll
    for (int ks = 0; ks < 4; ++ks) aq[ks] = *(const s16x8*)(qp + ks * 32 + g4 * 8);
  }
  f32x4 acco[8] = {};
  float mrun[4], lrun[4];
  #pragma unroll
  for (int j = 0; j < 4; ++j) { mrun[j] = -3.0e30f; lrun[j] = 0.f; }

  s16x8 kreg[4], vreg[4];
  auto loadt = [&](int tt) {
    const int kv0 = tt * 64;
    #pragma unroll
    for (int c = 0; c < 4; ++c) {
      const int b = c * 4096 + t * 16;
      kreg[c] = *(const s16x8*)(k + (size_t)(kv0 + (b >> 8)) * kH + h * kD + ((b & 255) >> 1));
      vreg[c] = *(const s16x8*)(vt + (size_t)(h * kD + (b >> 7)) * kS + kv0 + ((b & 127) >> 1));
    }
  };
  auto writet = [&](int buf) {
    #pragma unroll
    for (int c = 0; c < 4; ++c) {
      const int b = c * 4096 + t * 16;
      const int kr = b >> 8, kc = b & 255;
      *(s16x8*)((char*)Kl[buf] + kr * 256 + (kc ^ ((kr & 7) << 4))) = kreg[c];
      const int vr = b >> 7, vc = b & 127;
      *(s16x8*)((char*)Vl[buf] + vr * 128 + (vc ^ ((vr & 7) << 4))) = vreg[c];
    }
  };

  loadt(0);
  writet(0);
  __syncthreads();

  for (int tt = 0; tt <= qi; ++tt) {
    const int kv0 = tt * 64;
    const int cur = tt & 1;
    if (tt < qi) loadt(tt + 1);            // issue early; lands during compute

    // QK^T : 16 q-rows x 64 kv
    f32x4 sc[4] = {};
    __builtin_amdgcn_s_setprio(1);
    #pragma unroll
    for (int ks = 0; ks < 4; ++ks) {
      const int ch16 = ks * 4 + g4;
      #pragma unroll
      for (int nf = 0; nf < 4; ++nf) {
        const int row = nf * 16 + fr;
        const s16x8 bk =
            *(const s16x8*)((const char*)Kl[cur] + row * 256 + ((ch16 ^ (row & 7)) << 4));
        sc[nf] = __builtin_amdgcn_mfma_f32_16x16x32_bf16(aq[ks], bk, sc[nf], 0, 0, 0);
      }
    }
    __builtin_amdgcn_s_setprio(0);

    float val[4][4];
    #pragma unroll
    for (int nf = 0; nf < 4; ++nf) {
      #pragma unroll
      for (int j = 0; j < 4; ++j) {
        float v = sc[nf][j] * 0.08838834764831845f;
        if (tt == qi) {
          const int colg = kv0 + nf * 16 + fr;
          const int rowg = q0 + g4 * 4 + j;
          if (colg > rowg) v -= 1.0e9f;
        }
        val[nf][j] = v;
      }
    }

    #pragma unroll
    for (int j = 0; j < 4; ++j) {
      float rm = fmaxf(fmaxf(val[0][j], val[1][j]), fmaxf(val[2][j], val[3][j]));
      rm = fmaxf(rm, __shfl_xor(rm, 1));
      rm = fmaxf(rm, __shfl_xor(rm, 2));
      rm = fmaxf(rm, __shfl_xor(rm, 4));
      rm = fmaxf(rm, __shfl_xor(rm, 8));
      const float mnew = fmaxf(mrun[j], rm);
      const float corr = __expf(mrun[j] - mnew);
      mrun[j] = mnew;
      float ps = 0.f;
      #pragma unroll
      for (int nf = 0; nf < 4; ++nf) {
        const float p = __expf(val[nf][j] - mnew);
        ps += p;
        Pl[wid][(g4 * 4 + j) * 72 + nf * 16 + fr] = f2bs(p);
      }
      ps += __shfl_xor(ps, 1);
      ps += __shfl_xor(ps, 2);
      ps += __shfl_xor(ps, 4);
      ps += __shfl_xor(ps, 8);
      lrun[j] = lrun[j] * corr + ps;
      #pragma unroll
      for (int nf = 0; nf < 8; ++nf) acco[nf][j] *= corr;
    }

    // PV: P(16x64) @ V(64x128)
    __builtin_amdgcn_s_setprio(1);
    #pragma unroll
    for (int ks = 0; ks < 2; ++ks) {
      const s16x8 ap = *(const s16x8*)(&Pl[wid][fr * 72 + ks * 32 + g4 * 8]);
      const int ch16 = ks * 4 + g4;
      #pragma unroll
      for (int nf = 0; nf < 8; ++nf) {
        const int dd = nf * 16 + fr;
        const s16x8 bv =
            *(const s16x8*)((const char*)Vl[cur] + dd * 128 + ((ch16 ^ (dd & 7)) << 4));
        acco[nf] = __builtin_amdgcn_mfma_f32_16x16x32_bf16(ap, bv, acco[nf], 0, 0, 0);
      }
    }
    __builtin_amdgcn_s_setprio(0);

    if (tt < qi) writet(cur ^ 1);          // write-late into the other buffer
    __syncthreads();                       // single barrier per KV-step
  }

  #pragma unroll
  for (int nf = 0; nf < 8; ++nf) {
    #pragma unroll
    for (int j = 0; j < 4; ++j) {
      const int rowg = q0 + g4 * 4 + j;
      o[(size_t)rowg * kH + h * kD + nf * 16 + fr] = f2bs(acco[nf][j] / lrun[j]);
    }
  }
}

// ---------------------------------------------------------------------------
// silu(gate) * up, in place into g (bf16) — fallback path only
// ---------------------------------------------------------------------------
__global__ void silu_mul(short* __restrict__ g, const short* __restrict__ u, int n8) {
  for (int i = blockIdx.x * blockDim.x + threadIdx.x; i < n8; i += gridDim.x * blockDim.x) {
    const s16x8 gv = ((const s16x8*)g)[i];
    const s16x8 uv = ((const s16x8*)u)[i];
    s16x8 o;
    #pragma unroll
    for (int j = 0; j < 8; ++j) {
      const float gf = b2f(gv[j]);
      const float s = gf / (1.f + __expf(-gf));
      o[j] = f2bs(s * b2f(uv[j]));
    }
    ((s16x8*)g)[i] = o;
  }
}

// ---------------------------------------------------------------------------
extern "C" void kernel_launch(void* const* d_in, const int* in_sizes, int n_in,
                              void* d_out, int out_size, void* d_ws, size_t ws_size,
                              hipStream_t stream) {
  (void)in_sizes; (void)n_in; (void)out_size;
  const float* hidden = (const float*)d_in[0];
  const float* cosb = (const float*)d_in[2];
  const float* sinb = (const float*)d_in[3];
  const float* wq = (const float*)d_in[4];
  const float* wk = (const float*)d_in[5];
  const float* wv = (const float*)d_in[6];
  const float* wo = (const float*)d_in[7];
  const float* wg = (const float*)d_in[8];
  const float* wu = (const float*)d_in[9];
  const float* wd = (const float*)d_in[10];
  const float* ln1 = (const float*)d_in[11];
  const float* ln2 = (const float*)d_in[12];
  const int* pos = (const int*)d_in[13];
  float* out = (float*)d_out;

  // workspace layout
  char* p = (char*)d_ws;
  float* x  = (float*)p;  p += (size_t)kS * kH * 4;   // fp32 residual (16.8MB)
  short* hb = (short*)p;  p += (size_t)kS * kH * 2;   // normed acts (8.4MB)
  char* U = p;            p += (size_t)kS * kI * 4;   // union region (46.1MB)
  short* qb = (short*)(U);
  short* kb = (short*)(U + (size_t)kS * kH * 2);
  short* vtb = (short*)(U + (size_t)kS * kH * 4);     // V^T [H][S]
  short* ob = (short*)(U + (size_t)kS * kH * 6);      // attention out
  short* gb = (short*)(U);                            // act = silu(g)*u (MLP)
  short* ub = (short*)(U + (size_t)kS * kI * 2);      // up (fallback only)
  short* wbuf = (short*)p;                            // bf16 weights, one layer
  const size_t nHH = (size_t)kH * kH, nIH = (size_t)kI * kH;
  const size_t need = (size_t)(p - (char*)d_ws) + (4 * nHH + 3 * nIH) * 2;
  const bool pre = ws_size >= need;

  short* wqb = wbuf;            // q,k,v contiguous -> fused N=6144 B matrix
  short* wob = wqb + 3 * nHH;
  short* wgu = wob + nHH;       // INTERLEAVED gate/up -> N=11264 B matrix
  short* wdb = wgu + 2 * nIH;

  hipMemcpyAsync(x, hidden, (size_t)kS * kH * 4, hipMemcpyDeviceToDevice, stream);
  for (int l = 0; l < kL; ++l) {
    rmsnorm_k<<<kS, 256, 0, stream>>>(x, ln1 + (size_t)l * kH, hb);
    if (pre) {
      cvt_all<<<2048, 256, 0, stream>>>(wq + l * nHH, wk + l * nHH, wv + l * nHH,
                                        wo + l * nHH, wg + l * nIH, wu + l * nIH,
                                        wd + l * nIH, wbuf);
      // fused QKV: N = 6144 (grid 48x16 -> XCD rects 12x8)
      gemm_db<3><<<dim3(6144 / 128, kS / 128), 256, 0, stream>>>(
          hb, wqb, qb, kb, vtb, nullptr, kS, 6144, kH);
      rope_k<<<kS, 256, 0, stream>>>(qb, kb, cosb, sinb, pos);
      attn_k<<<dim3(kNH, kS / 64), 256, 0, stream>>>(qb, kb, vtb, ob);
      // o-proj: split-K=2 -> 512 blocks (2/CU), atomic fp32 residual add
      gemm_db<6><<<dim3(kH / 128, kS / 128, 2), 256, 0, stream>>>(
          ob, wob, nullptr, nullptr, nullptr, x, kS, kH, kH);
      rmsnorm_k<<<kS, 256, 0, stream>>>(x, ln2 + (size_t)l * kH, hb);
      // fused gate+up+silu: N = 11264 interleaved (grid 88x16), writes act
      gemm_db<5><<<dim3(11264 / 128, kS / 128), 256, 0, stream>>>(
          hb, wgu, gb, nullptr, nullptr, nullptr, kS, 11264, kH);
      // down: split-K=2 -> 512 blocks (2/CU), atomic fp32 residual add
      gemm_db<6><<<dim3(kH / 128, kS / 128, 2), 256, 0, stream>>>(
          gb, wdb, nullptr, nullptr, nullptr, x, kS, kH, kI);
    } else {
      gemm_btf<0><<<dim3(kH / 128, kS / 128), 256, 0, stream>>>(hb, wq + l * nHH, qb, nullptr, kS, kH, kH);
      gemm_btf<0><<<dim3(kH / 128, kS / 128), 256, 0, stream>>>(hb, wk + l * nHH, kb, nullptr, kS, kH, kH);
      gemm_btf<2><<<dim3(kH / 128, kS / 128), 256, 0, stream>>>(hb, wv + l * nHH, vtb, nullptr, kS, kH, kH);
      rope_k<<<kS, 256, 0, stream>>>(qb, kb, cosb, sinb, pos);
      attn_k<<<dim3(kNH, kS / 64), 256, 0, stream>>>(qb, kb, vtb, ob);
      gemm_btf<1><<<dim3(kH / 128, kS / 128), 256, 0, stream>>>(ob, wo + l * nHH, nullptr, x, kS, kH, kH);
      rmsnorm_k<<<kS, 256, 0, stream>>>(x, ln2 + (size_t)l * kH, hb);
      gemm_btf<0><<<dim3(kI / 128, kS / 128), 256, 0, stream>>>(hb, wg + l * nIH, gb, nullptr, kS, kI, kH);
      gemm_btf<0><<<dim3(kI / 128, kS / 128), 256, 0, stream>>>(hb, wu + l * nIH, ub, nullptr, kS, kI, kH);
      silu_mul<<<1408, 256, 0, stream>>>(gb, ub, kS * kI / 8);
      gemm_btf<1><<<dim3(kH / 128, kS / 128), 256, 0, stream>>>(gb, wd + l * nIH, nullptr, x, kS, kH, kI);
    }
  }
  hipMemcpyAsync(out, x, (size_t)kS * kH * 4, hipMemcpyDeviceToDevice, stream);
}